// Round 15
// baseline (236.042 us; speedup 1.0000x reference)
//
#include <hip/hip_runtime.h>
#include <hip/hip_bf16.h>

#define TT 512
#define BB 4096

typedef __attribute__((ext_vector_type(4))) float f32x4;
typedef __attribute__((ext_vector_type(8))) _Float16 f16x8;
typedef __attribute__((ext_vector_type(4))) unsigned int uint4v;

__device__ __forceinline__ f32x4 MFMA16(f16x8 a, f16x8 b, f32x4 c) {
    return __builtin_amdgcn_mfma_f32_16x16x32_f16(a, b, c, 0, 0, 0);
}
__device__ __forceinline__ float fast_rcp(float x) { return __builtin_amdgcn_rcpf(x); }
__device__ __forceinline__ unsigned int pkdup(float a) {
    return __builtin_bit_cast(unsigned int, __builtin_amdgcn_cvt_pkrtz(a, a));
}

// Polynomial exp2 on the FULL-RATE VALU pipe (displaces v_exp_f32 from the
// quarter-rate trans unit — R14 analysis: trans issue ~24-32 cyc/wave64 is the
// slot bottleneck). deg-5 Horner on fract, ldexp recombine; rel err ~2e-7.
// No range clamp: gate preacts are bounded |x| < ~40 by weight magnitudes.
__device__ __forceinline__ float poly_exp2(float x) {
    const float fl = floorf(x);
    const float f  = x - fl;
    float p = fmaf(f, 0.0018775767f, 0.0089893397f);
    p = fmaf(f, p, 0.0558021187f);
    p = fmaf(f, p, 0.2401596780f);
    p = fmaf(f, p, 0.6931471806f);
    p = fmaf(f, p, 1.0f);
    return ldexpf(p, (int)fl);
}

// log2e scaling folded into weights/biases (numerics validated R9-R14):
//   r,z rows x -log2e ; n rows x -2log2e ; gates use exp2.
#define KS1 (-1.44269504088896340736f)
#define KS2 (-2.88539008177792681472f)

// Layer-pipelined GRU (R14 structure, unchanged): 4 waves, 8 t/superstep,
//   waves 0..2 = layers (wave L does t=8(s-L)..+7), wave 3 = projection+stores.
// Block = 256 thr, one 16-batch tile; grid = 256 (1 block/CU, 1 wave/SIMD).
// f16 MFMA, K=32 pair-slot layout: A[2q] = scaled W[n][4g+q], A[2q+1]=0;
// B[2q]=B[2q+1]=v[4g+q] (pair-dup). Gate algebra (merged z/tanh denominator):
//   Er=2^{s_r'}, Ez=2^{s_z'}, En=2^{s_n'};  r = 1/(1+Er)
//   h' = [h(1+En) + Ez(1-En)] / [(1+Ez)(1+En)]  — one rcp for z+tanh.
__global__ __launch_bounds__(256, 1)
void gru_pe_kernel(const float* __restrict__ x, const float* __restrict__ h0,
                   const float* __restrict__ W_emb, const float* __restrict__ b_emb,
                   const float* __restrict__ W_out, const float* __restrict__ b_out,
                   const float* __restrict__ Wih0, const float* __restrict__ Whh0,
                   const float* __restrict__ bih0, const float* __restrict__ bhh0,
                   const float* __restrict__ Wih1, const float* __restrict__ Whh1,
                   const float* __restrict__ bih1, const float* __restrict__ bhh1,
                   const float* __restrict__ Wih2, const float* __restrict__ Whh2,
                   const float* __restrict__ bih2, const float* __restrict__ bhh2,
                   float* __restrict__ out)
{
    const int tid = threadIdx.x;
    const int wid = tid >> 6;      // 0..2 layer waves, 3 = projection wave
    const int l   = tid & 63;
    const int n   = l & 15;
    const int g   = l >> 4;
    const int b   = blockIdx.x * 16 + n;

    __shared__ uint4v lbuf[2][2][8][64];  // 32 KiB [parity][producer L][tslot][lane]
    __shared__ f32x4  obuf[2][8][64];     // 16 KiB [parity][tslot][lane] h2 f32

    const int lw = wid < 3 ? wid : 2;
    const float* Wih = lw == 0 ? Wih0 : (lw == 1 ? Wih1 : Wih2);
    const float* Whh = lw == 0 ? Whh0 : (lw == 1 ? Whh1 : Whh2);
    const float* bih = lw == 0 ? bih0 : (lw == 1 ? bih1 : bih2);
    const float* bhh = lw == 0 ? bhh0 : (lw == 1 ? bhh1 : bhh2);

    // A-fragments, f16, log2e-scale folded: gates 0,1 (r,z) x KS1; gate 2 (n) x KS2.
    f16x8 aX[3], aH[3];
#pragma unroll
    for (int gate = 0; gate < 3; ++gate) {
        const float ks = (gate == 2) ? KS2 : KS1;
        f16x8 fx, fh;
#pragma unroll
        for (int q = 0; q < 4; ++q) {
            fx[2 * q]     = (_Float16)(ks * Wih[(gate * 16 + n) * 16 + 4 * g + q]);
            fx[2 * q + 1] = (_Float16)0.0f;
            fh[2 * q]     = (_Float16)(ks * Whh[(gate * 16 + n) * 16 + 4 * g + q]);
            fh[2 * q + 1] = (_Float16)0.0f;
        }
        aX[gate] = fx; aH[gate] = fh;
    }

    // Scaled biases in C layout (row m = 4g+j)
    f32x4 bR, bZ, bNX, bNH;
#pragma unroll
    for (int j = 0; j < 4; ++j) {
        const int m = 4 * g + j;
        bR[j]  = KS1 * (bih[m]      + bhh[m]);
        bZ[j]  = KS1 * (bih[16 + m] + bhh[16 + m]);
        bNX[j] = KS2 * bih[32 + m];
        bNH[j] = KS2 * bhh[32 + m];
    }

    // Embedding rows c = 4g+q (wave 0; e UNSCALED — scale lives in A)
    float wex[4], wey[4], beq[4];
#pragma unroll
    for (int q = 0; q < 4; ++q) {
        const int c = 4 * g + q;
        wex[q] = W_emb[c * 2]; wey[q] = W_emb[c * 2 + 1]; beq[q] = b_emb[c];
    }
    // Output weights rows m = 4g+j (wave 3)
    float wo0[4], wo1[4];
#pragma unroll
    for (int j = 0; j < 4; ++j) { wo0[j] = W_out[4 * g + j]; wo1[j] = W_out[16 + 4 * g + j]; }
    const float bo0 = b_out[0], bo1 = b_out[1];

    // Hidden state: f32 C rows + dup'd f16 B fragment
    f32x4 hC = *(const f32x4*)(h0 + ((size_t)lw * BB + b) * 16 + 4 * g);
    uint4v hB4;
#pragma unroll
    for (int q = 0; q < 4; ++q) hB4[q] = pkdup(hC[q]);

    const float* xb = x + (size_t)b * (TT * 2);
    float4 xc[4];
    if (wid == 0) {
#pragma unroll
        for (int q = 0; q < 4; ++q) xc[q] = *(const float4*)(xb + 4 * q);  // t=0..7
    }

#define HB() __builtin_bit_cast(f16x8, hB4)

#define GATES(AR, AZ, ANH, ANX)                                           \
    do {                                                                  \
        _Pragma("unroll")                                                 \
        for (int j = 0; j < 4; ++j) {                                     \
            const float Er  = poly_exp2(AR[j]);                           \
            const float Ez  = poly_exp2(AZ[j]);                           \
            const float r   = fast_rcp(1.0f + Er);                        \
            const float En  = poly_exp2(fmaf(r, ANH[j], ANX[j]));         \
            const float oEz = 1.0f + Ez;                                  \
            const float num = fmaf(En, hC[j] - Ez, hC[j] + Ez);           \
            const float den = fmaf(oEz, En, oEz);                         \
            hC[j] = num * fast_rcp(den);                                  \
        }                                                                 \
        _Pragma("unroll")                                                 \
        for (int q = 0; q < 4; ++q) hB4[q] = pkdup(hC[q]);                \
    } while (0)

#define HANDOFF(i)                                                        \
    do {                                                                  \
        if (wid < 2) lbuf[s & 1][wid][i][l] = hB4;                        \
        else         obuf[s & 1][i][l] = hC;                              \
    } while (0)

    const int NS = TT / 8 + 3;   // 67 supersteps
    for (int s = 0; s < NS; ++s) {
        const int t0 = 8 * (s - wid);
        if (t0 >= 0 && t0 < TT) {
            if (wid < 3) {
                // ---- input B-fragments (dup'd f16) for t0..t0+7 ----
                f16x8 Bv[8];
                if (wid == 0) {
#pragma unroll
                    for (int i = 0; i < 4; ++i) {
                        uint4v ua, ub;
#pragma unroll
                        for (int q = 0; q < 4; ++q) {
                            ua[q] = pkdup(fmaxf(fmaf(wey[q], xc[i].y, fmaf(wex[q], xc[i].x, beq[q])), 0.0f));
                            ub[q] = pkdup(fmaxf(fmaf(wey[q], xc[i].w, fmaf(wex[q], xc[i].z, beq[q])), 0.0f));
                        }
                        Bv[2 * i]     = __builtin_bit_cast(f16x8, ua);
                        Bv[2 * i + 1] = __builtin_bit_cast(f16x8, ub);
                    }
                    if (t0 + 8 < TT) {
#pragma unroll
                        for (int q = 0; q < 4; ++q)
                            xc[q] = *(const float4*)(xb + (t0 + 8) * 2 + 4 * q);
                    }
                } else {
                    const int pp = (s - 1) & 1;
#pragma unroll
                    for (int i = 0; i < 8; ++i)
                        Bv[i] = __builtin_bit_cast(f16x8, lbuf[pp][wid - 1][i][l]);
                }

                // ---- 8 slots, rolling A/B register pattern (R12/R14 schedule) ----
                f32x4 arA = MFMA16(aX[0], Bv[0], bR);   // pre-issue slot 0 x-side
                f32x4 azA = MFMA16(aX[1], Bv[0], bZ);
                f32x4 axA = MFMA16(aX[2], Bv[0], bNX);
                f32x4 arB, azB, axB, anh;
#pragma unroll
                for (int i = 0; i < 8; i += 2) {
                    // slot i (A regs)
                    anh = MFMA16(aH[2], HB(), bNH);
                    arA = MFMA16(aH[0], HB(), arA);
                    azA = MFMA16(aH[1], HB(), azA);
                    arB = MFMA16(aX[0], Bv[i + 1], bR);   // pre-issue slot i+1
                    azB = MFMA16(aX[1], Bv[i + 1], bZ);
                    axB = MFMA16(aX[2], Bv[i + 1], bNX);
                    GATES(arA, azA, anh, axA);
                    HANDOFF(i);
                    // slot i+1 (B regs)
                    anh = MFMA16(aH[2], HB(), bNH);
                    arB = MFMA16(aH[0], HB(), arB);
                    azB = MFMA16(aH[1], HB(), azB);
                    if (i + 2 < 8) {
                        arA = MFMA16(aX[0], Bv[i + 2], bR);  // pre-issue slot i+2
                        azA = MFMA16(aX[1], Bv[i + 2], bZ);
                        axA = MFMA16(aX[2], Bv[i + 2], bNX);
                    }
                    GATES(arB, azB, anh, axB);
                    HANDOFF(i + 1);
                }
            } else {
                // ---- projection wave: t0..t0+7 (h2 from wave2, superstep s-1) ----
                const int pp = (s - 1) & 1;
#pragma unroll
                for (int h = 0; h < 2; ++h) {
                    float pr[8];
#pragma unroll
                    for (int i = 0; i < 4; ++i) {
                        const f32x4 h2 = obuf[pp][4 * h + i][l];
                        float p0 = 0.f, p1 = 0.f;
#pragma unroll
                        for (int j = 0; j < 4; ++j) {
                            p0 = fmaf(wo0[j], h2[j], p0);
                            p1 = fmaf(wo1[j], h2[j], p1);
                        }
                        p0 += __shfl_xor(p0, 16); p0 += __shfl_xor(p0, 32);
                        p1 += __shfl_xor(p1, 16); p1 += __shfl_xor(p1, 32);
                        pr[2 * i] = p0 + bo0; pr[2 * i + 1] = p1 + bo1;
                    }
                    if (g == 0) {
                        float* op = out + (size_t)b * (TT * 2) + (t0 + 4 * h) * 2;
                        *(float4*)(op)     = make_float4(pr[0], pr[1], pr[2], pr[3]);
                        *(float4*)(op + 4) = make_float4(pr[4], pr[5], pr[6], pr[7]);
                    }
                }
            }
        }
        // LDS-only barrier: drain ds ops, fence compiler, s_barrier.
        // vm loads/stores (x prefetch, out stores) deliberately stay in flight.
        asm volatile("s_waitcnt lgkmcnt(0)\n\ts_barrier" ::: "memory");
    }

    // Final hidden state: layer waves store their own layer.
    if (wid < 3)
        *(f32x4*)(out + (size_t)BB * TT * 2 + ((size_t)wid * BB + b) * 16 + 4 * g) = hC;

#undef GATES
#undef HANDOFF
#undef HB
}

extern "C" void kernel_launch(void* const* d_in, const int* in_sizes, int n_in,
                              void* d_out, int out_size, void* d_ws, size_t ws_size,
                              hipStream_t stream) {
    const float* x     = (const float*)d_in[0];
    const float* h0    = (const float*)d_in[1];
    const float* W_emb = (const float*)d_in[2];
    const float* b_emb = (const float*)d_in[3];
    const float* W_out = (const float*)d_in[4];
    const float* b_out = (const float*)d_in[5];
    const float* Wih0  = (const float*)d_in[6];
    const float* Whh0  = (const float*)d_in[7];
    const float* bih0  = (const float*)d_in[8];
    const float* bhh0  = (const float*)d_in[9];
    const float* Wih1  = (const float*)d_in[10];
    const float* Whh1  = (const float*)d_in[11];
    const float* bih1  = (const float*)d_in[12];
    const float* bhh1  = (const float*)d_in[13];
    const float* Wih2  = (const float*)d_in[14];
    const float* Whh2  = (const float*)d_in[15];
    const float* bih2  = (const float*)d_in[16];
    const float* bhh2  = (const float*)d_in[17];
    float* out = (float*)d_out;

    gru_pe_kernel<<<dim3(BB / 16), dim3(256), 0, stream>>>(
        x, h0, W_emb, b_emb, W_out, b_out,
        Wih0, Whh0, bih0, bhh0,
        Wih1, Whh1, bih1, bhh1,
        Wih2, Whh2, bih2, bhh2,
        out);
}

// Round 16
// 160.543 us; speedup vs baseline: 1.4703x; 1.4703x over previous
//
#include <hip/hip_runtime.h>
#include <hip/hip_bf16.h>

#define TT 512
#define BB 4096

typedef __attribute__((ext_vector_type(4))) float f32x4;
typedef __attribute__((ext_vector_type(8))) _Float16 f16x8;
typedef __attribute__((ext_vector_type(4))) unsigned int uint4v;

__device__ __forceinline__ f32x4 MFMA16(f16x8 a, f16x8 b, f32x4 c) {
    return __builtin_amdgcn_mfma_f32_16x16x32_f16(a, b, c, 0, 0, 0);
}
__device__ __forceinline__ float fast_rcp(float x) { return __builtin_amdgcn_rcpf(x); }
__device__ __forceinline__ float fast_exp2(float x) { return __builtin_amdgcn_exp2f(x); }
__device__ __forceinline__ unsigned int pkdup(float a) {
    return __builtin_bit_cast(unsigned int, __builtin_amdgcn_cvt_pkrtz(a, a));
}

// log2e scaling folded into weights/biases (numerics validated R9-R14):
//   r,z rows x -log2e ; n rows x -2log2e ; gates use bare v_exp_f32 (exp2).
#define KS1 (-1.44269504088896340736f)
#define KS2 (-2.88539008177792681472f)

// Layer-pipelined GRU (R14, best measured: 161 us): 4 waves, 8 t/superstep,
//   waves 0..2 = layers (wave L does t=8(s-L)..+7), wave 3 = projection+stores.
// Block = 256 thr, one 16-batch tile; grid = 256 (1 block/CU, 1 wave/SIMD).
// f16 MFMA, K=32 pair-slot layout: A[2q] = scaled W[n][4g+q], A[2q+1]=0;
// B[2q]=B[2q+1]=v[4g+q] (pair-dup). Gate algebra (merged z/tanh denominator):
//   Er=2^{s_r'}, Ez=2^{s_z'}, En=2^{s_n'};  r = 1/(1+Er)
//   h' = [h(1+En) + Ez(1-En)] / [(1+Ez)(1+En)]  — one rcp for z+tanh.
// Slot schedule: rolling A/B pattern; h-side MFMAs, pre-issue next slot's
// x-MFMAs, then the 4-j gate chains (hardware v_exp_f32 — R13/R15 both showed
// any synthetic replacement of the gate region regresses).
__global__ __launch_bounds__(256, 1)
void gru_p8_kernel(const float* __restrict__ x, const float* __restrict__ h0,
                   const float* __restrict__ W_emb, const float* __restrict__ b_emb,
                   const float* __restrict__ W_out, const float* __restrict__ b_out,
                   const float* __restrict__ Wih0, const float* __restrict__ Whh0,
                   const float* __restrict__ bih0, const float* __restrict__ bhh0,
                   const float* __restrict__ Wih1, const float* __restrict__ Whh1,
                   const float* __restrict__ bih1, const float* __restrict__ bhh1,
                   const float* __restrict__ Wih2, const float* __restrict__ Whh2,
                   const float* __restrict__ bih2, const float* __restrict__ bhh2,
                   float* __restrict__ out)
{
    const int tid = threadIdx.x;
    const int wid = tid >> 6;      // 0..2 layer waves, 3 = projection wave
    const int l   = tid & 63;
    const int n   = l & 15;
    const int g   = l >> 4;
    const int b   = blockIdx.x * 16 + n;

    __shared__ uint4v lbuf[2][2][8][64];  // 32 KiB [parity][producer L][tslot][lane]
    __shared__ f32x4  obuf[2][8][64];     // 16 KiB [parity][tslot][lane] h2 f32

    const int lw = wid < 3 ? wid : 2;
    const float* Wih = lw == 0 ? Wih0 : (lw == 1 ? Wih1 : Wih2);
    const float* Whh = lw == 0 ? Whh0 : (lw == 1 ? Whh1 : Whh2);
    const float* bih = lw == 0 ? bih0 : (lw == 1 ? bih1 : bih2);
    const float* bhh = lw == 0 ? bhh0 : (lw == 1 ? bhh1 : bhh2);

    // A-fragments, f16, log2e-scale folded: gates 0,1 (r,z) x KS1; gate 2 (n) x KS2.
    f16x8 aX[3], aH[3];
#pragma unroll
    for (int gate = 0; gate < 3; ++gate) {
        const float ks = (gate == 2) ? KS2 : KS1;
        f16x8 fx, fh;
#pragma unroll
        for (int q = 0; q < 4; ++q) {
            fx[2 * q]     = (_Float16)(ks * Wih[(gate * 16 + n) * 16 + 4 * g + q]);
            fx[2 * q + 1] = (_Float16)0.0f;
            fh[2 * q]     = (_Float16)(ks * Whh[(gate * 16 + n) * 16 + 4 * g + q]);
            fh[2 * q + 1] = (_Float16)0.0f;
        }
        aX[gate] = fx; aH[gate] = fh;
    }

    // Scaled biases in C layout (row m = 4g+j)
    f32x4 bR, bZ, bNX, bNH;
#pragma unroll
    for (int j = 0; j < 4; ++j) {
        const int m = 4 * g + j;
        bR[j]  = KS1 * (bih[m]      + bhh[m]);
        bZ[j]  = KS1 * (bih[16 + m] + bhh[16 + m]);
        bNX[j] = KS2 * bih[32 + m];
        bNH[j] = KS2 * bhh[32 + m];
    }

    // Embedding rows c = 4g+q (wave 0; e UNSCALED — scale lives in A)
    float wex[4], wey[4], beq[4];
#pragma unroll
    for (int q = 0; q < 4; ++q) {
        const int c = 4 * g + q;
        wex[q] = W_emb[c * 2]; wey[q] = W_emb[c * 2 + 1]; beq[q] = b_emb[c];
    }
    // Output weights rows m = 4g+j (wave 3)
    float wo0[4], wo1[4];
#pragma unroll
    for (int j = 0; j < 4; ++j) { wo0[j] = W_out[4 * g + j]; wo1[j] = W_out[16 + 4 * g + j]; }
    const float bo0 = b_out[0], bo1 = b_out[1];

    // Hidden state: f32 C rows + dup'd f16 B fragment
    f32x4 hC = *(const f32x4*)(h0 + ((size_t)lw * BB + b) * 16 + 4 * g);
    uint4v hB4;
#pragma unroll
    for (int q = 0; q < 4; ++q) hB4[q] = pkdup(hC[q]);

    const float* xb = x + (size_t)b * (TT * 2);
    float4 xc[4];
    if (wid == 0) {
#pragma unroll
        for (int q = 0; q < 4; ++q) xc[q] = *(const float4*)(xb + 4 * q);  // t=0..7
    }

#define HB() __builtin_bit_cast(f16x8, hB4)

#define GATES(AR, AZ, ANH, ANX)                                           \
    do {                                                                  \
        _Pragma("unroll")                                                 \
        for (int j = 0; j < 4; ++j) {                                     \
            const float Er = fast_exp2(AR[j]);                            \
            const float Ez = fast_exp2(AZ[j]);                            \
            const float r  = fast_rcp(1.0f + Er);                         \
            const float En = fast_exp2(fmaf(r, ANH[j], ANX[j]));          \
            const float num = fmaf(En, hC[j] - Ez, hC[j] + Ez);           \
            const float den = fmaf(En, Ez, En) + (1.0f + Ez);             \
            hC[j] = num * fast_rcp(den);                                  \
        }                                                                 \
        _Pragma("unroll")                                                 \
        for (int q = 0; q < 4; ++q) hB4[q] = pkdup(hC[q]);                \
    } while (0)

#define HANDOFF(i)                                                        \
    do {                                                                  \
        if (wid < 2) lbuf[s & 1][wid][i][l] = hB4;                        \
        else         obuf[s & 1][i][l] = hC;                              \
    } while (0)

    const int NS = TT / 8 + 3;   // 67 supersteps
    for (int s = 0; s < NS; ++s) {
        const int t0 = 8 * (s - wid);
        if (t0 >= 0 && t0 < TT) {
            if (wid < 3) {
                // ---- input B-fragments (dup'd f16) for t0..t0+7 ----
                f16x8 Bv[8];
                if (wid == 0) {
#pragma unroll
                    for (int i = 0; i < 4; ++i) {
                        uint4v ua, ub;
#pragma unroll
                        for (int q = 0; q < 4; ++q) {
                            ua[q] = pkdup(fmaxf(fmaf(wey[q], xc[i].y, fmaf(wex[q], xc[i].x, beq[q])), 0.0f));
                            ub[q] = pkdup(fmaxf(fmaf(wey[q], xc[i].w, fmaf(wex[q], xc[i].z, beq[q])), 0.0f));
                        }
                        Bv[2 * i]     = __builtin_bit_cast(f16x8, ua);
                        Bv[2 * i + 1] = __builtin_bit_cast(f16x8, ub);
                    }
                    if (t0 + 8 < TT) {
#pragma unroll
                        for (int q = 0; q < 4; ++q)
                            xc[q] = *(const float4*)(xb + (t0 + 8) * 2 + 4 * q);
                    }
                } else {
                    const int pp = (s - 1) & 1;
#pragma unroll
                    for (int i = 0; i < 8; ++i)
                        Bv[i] = __builtin_bit_cast(f16x8, lbuf[pp][wid - 1][i][l]);
                }

                // ---- 8 slots, rolling A/B register pattern (R12/R14 schedule) ----
                f32x4 arA = MFMA16(aX[0], Bv[0], bR);   // pre-issue slot 0 x-side
                f32x4 azA = MFMA16(aX[1], Bv[0], bZ);
                f32x4 axA = MFMA16(aX[2], Bv[0], bNX);
                f32x4 arB, azB, axB, anh;
#pragma unroll
                for (int i = 0; i < 8; i += 2) {
                    // slot i (A regs)
                    anh = MFMA16(aH[2], HB(), bNH);
                    arA = MFMA16(aH[0], HB(), arA);
                    azA = MFMA16(aH[1], HB(), azA);
                    arB = MFMA16(aX[0], Bv[i + 1], bR);   // pre-issue slot i+1
                    azB = MFMA16(aX[1], Bv[i + 1], bZ);
                    axB = MFMA16(aX[2], Bv[i + 1], bNX);
                    GATES(arA, azA, anh, axA);
                    HANDOFF(i);
                    // slot i+1 (B regs)
                    anh = MFMA16(aH[2], HB(), bNH);
                    arB = MFMA16(aH[0], HB(), arB);
                    azB = MFMA16(aH[1], HB(), azB);
                    if (i + 2 < 8) {
                        arA = MFMA16(aX[0], Bv[i + 2], bR);  // pre-issue slot i+2
                        azA = MFMA16(aX[1], Bv[i + 2], bZ);
                        axA = MFMA16(aX[2], Bv[i + 2], bNX);
                    }
                    GATES(arB, azB, anh, axB);
                    HANDOFF(i + 1);
                }
            } else {
                // ---- projection wave: t0..t0+7 (h2 from wave2, superstep s-1) ----
                const int pp = (s - 1) & 1;
#pragma unroll
                for (int h = 0; h < 2; ++h) {
                    float pr[8];
#pragma unroll
                    for (int i = 0; i < 4; ++i) {
                        const f32x4 h2 = obuf[pp][4 * h + i][l];
                        float p0 = 0.f, p1 = 0.f;
#pragma unroll
                        for (int j = 0; j < 4; ++j) {
                            p0 = fmaf(wo0[j], h2[j], p0);
                            p1 = fmaf(wo1[j], h2[j], p1);
                        }
                        p0 += __shfl_xor(p0, 16); p0 += __shfl_xor(p0, 32);
                        p1 += __shfl_xor(p1, 16); p1 += __shfl_xor(p1, 32);
                        pr[2 * i] = p0 + bo0; pr[2 * i + 1] = p1 + bo1;
                    }
                    if (g == 0) {
                        float* op = out + (size_t)b * (TT * 2) + (t0 + 4 * h) * 2;
                        *(float4*)(op)     = make_float4(pr[0], pr[1], pr[2], pr[3]);
                        *(float4*)(op + 4) = make_float4(pr[4], pr[5], pr[6], pr[7]);
                    }
                }
            }
        }
        // LDS-only barrier: drain ds ops, fence compiler, s_barrier.
        // vm loads/stores (x prefetch, out stores) deliberately stay in flight.
        asm volatile("s_waitcnt lgkmcnt(0)\n\ts_barrier" ::: "memory");
    }

    // Final hidden state: layer waves store their own layer.
    if (wid < 3)
        *(f32x4*)(out + (size_t)BB * TT * 2 + ((size_t)wid * BB + b) * 16 + 4 * g) = hC;

#undef GATES
#undef HANDOFF
#undef HB
}

extern "C" void kernel_launch(void* const* d_in, const int* in_sizes, int n_in,
                              void* d_out, int out_size, void* d_ws, size_t ws_size,
                              hipStream_t stream) {
    const float* x     = (const float*)d_in[0];
    const float* h0    = (const float*)d_in[1];
    const float* W_emb = (const float*)d_in[2];
    const float* b_emb = (const float*)d_in[3];
    const float* W_out = (const float*)d_in[4];
    const float* b_out = (const float*)d_in[5];
    const float* Wih0  = (const float*)d_in[6];
    const float* Whh0  = (const float*)d_in[7];
    const float* bih0  = (const float*)d_in[8];
    const float* bhh0  = (const float*)d_in[9];
    const float* Wih1  = (const float*)d_in[10];
    const float* Whh1  = (const float*)d_in[11];
    const float* bih1  = (const float*)d_in[12];
    const float* bhh1  = (const float*)d_in[13];
    const float* Wih2  = (const float*)d_in[14];
    const float* Whh2  = (const float*)d_in[15];
    const float* bih2  = (const float*)d_in[16];
    const float* bhh2  = (const float*)d_in[17];
    float* out = (float*)d_out;

    gru_p8_kernel<<<dim3(BB / 16), dim3(256), 0, stream>>>(
        x, h0, W_emb, b_emb, W_out, b_out,
        Wih0, Whh0, bih0, bhh0,
        Wih1, Whh1, bih1, bhh1,
        Wih2, Whh2, bih2, bhh2,
        out);
}

// Round 17
// 159.692 us; speedup vs baseline: 1.4781x; 1.0053x over previous
//
#include <hip/hip_runtime.h>
#include <hip/hip_bf16.h>

#define TT 512
#define BB 4096

typedef __attribute__((ext_vector_type(4))) float f32x4;
typedef __attribute__((ext_vector_type(8))) _Float16 f16x8;
typedef __attribute__((ext_vector_type(4))) unsigned int uint4v;

__device__ __forceinline__ f32x4 MFMA16(f16x8 a, f16x8 b, f32x4 c) {
    return __builtin_amdgcn_mfma_f32_16x16x32_f16(a, b, c, 0, 0, 0);
}
__device__ __forceinline__ float fast_rcp(float x) { return __builtin_amdgcn_rcpf(x); }
__device__ __forceinline__ float fast_exp2(float x) { return __builtin_amdgcn_exp2f(x); }
__device__ __forceinline__ unsigned int pkdup(float a) {
    return __builtin_bit_cast(unsigned int, __builtin_amdgcn_cvt_pkrtz(a, a));
}

// log2e scaling folded into weights/biases (numerics validated R9-R16):
//   r,z rows x -log2e ; n rows x -2log2e ; gates use bare v_exp_f32 (exp2).
#define KS1 (-1.44269504088896340736f)
#define KS2 (-2.88539008177792681472f)

// Layer-pipelined GRU (R14/R16 structure, 16 t/superstep): 4 waves,
//   waves 0..2 = layers (wave L does t=16(s-L)..+15), wave 3 = projection+stores.
// Block = 256 thr, one 16-batch tile; grid = 256 (1 block/CU, 1 wave/SIMD).
// f16 MFMA, K=32 pair-slot layout: A[2q] = scaled W[n][4g+q], A[2q+1]=0;
// B[2q]=B[2q+1]=v[4g+q] (pair-dup). Gate algebra (merged z/tanh denominator):
//   Er=2^{s_r'}, Ez=2^{s_z'}, En=2^{s_n'};  r = 1/(1+Er)
//   h' = [h(1+En) + Ez(1-En)] / [(1+Ez)(1+En)]  — one rcp for z+tanh.
// 16 slots/superstep halves the fixed barrier+skew cost vs R16 (the only
// twice-validated remaining lever: R7->R8, R13->R14). LDS 96 KiB (<160/CU).
__global__ __launch_bounds__(256, 1)
void gru_p16_kernel(const float* __restrict__ x, const float* __restrict__ h0,
                    const float* __restrict__ W_emb, const float* __restrict__ b_emb,
                    const float* __restrict__ W_out, const float* __restrict__ b_out,
                    const float* __restrict__ Wih0, const float* __restrict__ Whh0,
                    const float* __restrict__ bih0, const float* __restrict__ bhh0,
                    const float* __restrict__ Wih1, const float* __restrict__ Whh1,
                    const float* __restrict__ bih1, const float* __restrict__ bhh1,
                    const float* __restrict__ Wih2, const float* __restrict__ Whh2,
                    const float* __restrict__ bih2, const float* __restrict__ bhh2,
                    float* __restrict__ out)
{
    const int tid = threadIdx.x;
    const int wid = tid >> 6;      // 0..2 layer waves, 3 = projection wave
    const int l   = tid & 63;
    const int n   = l & 15;
    const int g   = l >> 4;
    const int b   = blockIdx.x * 16 + n;

    __shared__ uint4v lbuf[2][2][16][64];  // 64 KiB [parity][producer L][tslot][lane]
    __shared__ f32x4  obuf[2][16][64];     // 32 KiB [parity][tslot][lane] h2 f32

    const int lw = wid < 3 ? wid : 2;
    const float* Wih = lw == 0 ? Wih0 : (lw == 1 ? Wih1 : Wih2);
    const float* Whh = lw == 0 ? Whh0 : (lw == 1 ? Whh1 : Whh2);
    const float* bih = lw == 0 ? bih0 : (lw == 1 ? bih1 : bih2);
    const float* bhh = lw == 0 ? bhh0 : (lw == 1 ? bhh1 : bhh2);

    // A-fragments, f16, log2e-scale folded: gates 0,1 (r,z) x KS1; gate 2 (n) x KS2.
    f16x8 aX[3], aH[3];
#pragma unroll
    for (int gate = 0; gate < 3; ++gate) {
        const float ks = (gate == 2) ? KS2 : KS1;
        f16x8 fx, fh;
#pragma unroll
        for (int q = 0; q < 4; ++q) {
            fx[2 * q]     = (_Float16)(ks * Wih[(gate * 16 + n) * 16 + 4 * g + q]);
            fx[2 * q + 1] = (_Float16)0.0f;
            fh[2 * q]     = (_Float16)(ks * Whh[(gate * 16 + n) * 16 + 4 * g + q]);
            fh[2 * q + 1] = (_Float16)0.0f;
        }
        aX[gate] = fx; aH[gate] = fh;
    }

    // Scaled biases in C layout (row m = 4g+j)
    f32x4 bR, bZ, bNX, bNH;
#pragma unroll
    for (int j = 0; j < 4; ++j) {
        const int m = 4 * g + j;
        bR[j]  = KS1 * (bih[m]      + bhh[m]);
        bZ[j]  = KS1 * (bih[16 + m] + bhh[16 + m]);
        bNX[j] = KS2 * bih[32 + m];
        bNH[j] = KS2 * bhh[32 + m];
    }

    // Embedding rows c = 4g+q (wave 0; e UNSCALED — scale lives in A)
    float wex[4], wey[4], beq[4];
#pragma unroll
    for (int q = 0; q < 4; ++q) {
        const int c = 4 * g + q;
        wex[q] = W_emb[c * 2]; wey[q] = W_emb[c * 2 + 1]; beq[q] = b_emb[c];
    }
    // Output weights rows m = 4g+j (wave 3)
    float wo0[4], wo1[4];
#pragma unroll
    for (int j = 0; j < 4; ++j) { wo0[j] = W_out[4 * g + j]; wo1[j] = W_out[16 + 4 * g + j]; }
    const float bo0 = b_out[0], bo1 = b_out[1];

    // Hidden state: f32 C rows + dup'd f16 B fragment
    f32x4 hC = *(const f32x4*)(h0 + ((size_t)lw * BB + b) * 16 + 4 * g);
    uint4v hB4;
#pragma unroll
    for (int q = 0; q < 4; ++q) hB4[q] = pkdup(hC[q]);

    const float* xb = x + (size_t)b * (TT * 2);
    float4 xc[8];
    if (wid == 0) {
#pragma unroll
        for (int q = 0; q < 8; ++q) xc[q] = *(const float4*)(xb + 4 * q);  // t=0..15
    }

#define HB() __builtin_bit_cast(f16x8, hB4)

#define GATES(AR, AZ, ANH, ANX)                                           \
    do {                                                                  \
        _Pragma("unroll")                                                 \
        for (int j = 0; j < 4; ++j) {                                     \
            const float Er = fast_exp2(AR[j]);                            \
            const float Ez = fast_exp2(AZ[j]);                            \
            const float r  = fast_rcp(1.0f + Er);                         \
            const float En = fast_exp2(fmaf(r, ANH[j], ANX[j]));          \
            const float num = fmaf(En, hC[j] - Ez, hC[j] + Ez);           \
            const float den = fmaf(En, Ez, En) + (1.0f + Ez);             \
            hC[j] = num * fast_rcp(den);                                  \
        }                                                                 \
        _Pragma("unroll")                                                 \
        for (int q = 0; q < 4; ++q) hB4[q] = pkdup(hC[q]);                \
    } while (0)

#define HANDOFF(i)                                                        \
    do {                                                                  \
        if (wid < 2) lbuf[s & 1][wid][i][l] = hB4;                        \
        else         obuf[s & 1][i][l] = hC;                              \
    } while (0)

    const int NS = TT / 16 + 3;   // 35 supersteps
    for (int s = 0; s < NS; ++s) {
        const int t0 = 16 * (s - wid);
        if (t0 >= 0 && t0 < TT) {
            if (wid < 3) {
                // ---- input B-fragments (dup'd f16) for t0..t0+15 ----
                f16x8 Bv[16];
                if (wid == 0) {
#pragma unroll
                    for (int i = 0; i < 8; ++i) {
                        uint4v ua, ub;
#pragma unroll
                        for (int q = 0; q < 4; ++q) {
                            ua[q] = pkdup(fmaxf(fmaf(wey[q], xc[i].y, fmaf(wex[q], xc[i].x, beq[q])), 0.0f));
                            ub[q] = pkdup(fmaxf(fmaf(wey[q], xc[i].w, fmaf(wex[q], xc[i].z, beq[q])), 0.0f));
                        }
                        Bv[2 * i]     = __builtin_bit_cast(f16x8, ua);
                        Bv[2 * i + 1] = __builtin_bit_cast(f16x8, ub);
                    }
                    if (t0 + 16 < TT) {
#pragma unroll
                        for (int q = 0; q < 8; ++q)
                            xc[q] = *(const float4*)(xb + (t0 + 16) * 2 + 4 * q);
                    }
                } else {
                    const int pp = (s - 1) & 1;
#pragma unroll
                    for (int i = 0; i < 16; ++i)
                        Bv[i] = __builtin_bit_cast(f16x8, lbuf[pp][wid - 1][i][l]);
                }

                // ---- 16 slots, rolling A/B register pattern (R12/R14 schedule) ----
                f32x4 arA = MFMA16(aX[0], Bv[0], bR);   // pre-issue slot 0 x-side
                f32x4 azA = MFMA16(aX[1], Bv[0], bZ);
                f32x4 axA = MFMA16(aX[2], Bv[0], bNX);
                f32x4 arB, azB, axB, anh;
#pragma unroll
                for (int i = 0; i < 16; i += 2) {
                    // slot i (A regs)
                    anh = MFMA16(aH[2], HB(), bNH);
                    arA = MFMA16(aH[0], HB(), arA);
                    azA = MFMA16(aH[1], HB(), azA);
                    arB = MFMA16(aX[0], Bv[i + 1], bR);   // pre-issue slot i+1
                    azB = MFMA16(aX[1], Bv[i + 1], bZ);
                    axB = MFMA16(aX[2], Bv[i + 1], bNX);
                    GATES(arA, azA, anh, axA);
                    HANDOFF(i);
                    // slot i+1 (B regs)
                    anh = MFMA16(aH[2], HB(), bNH);
                    arB = MFMA16(aH[0], HB(), arB);
                    azB = MFMA16(aH[1], HB(), azB);
                    if (i + 2 < 16) {
                        arA = MFMA16(aX[0], Bv[i + 2], bR);  // pre-issue slot i+2
                        azA = MFMA16(aX[1], Bv[i + 2], bZ);
                        axA = MFMA16(aX[2], Bv[i + 2], bNX);
                    }
                    GATES(arB, azB, anh, axB);
                    HANDOFF(i + 1);
                }
            } else {
                // ---- projection wave: t0..t0+15 (h2 from wave2, superstep s-1) ----
                const int pp = (s - 1) & 1;
#pragma unroll
                for (int h = 0; h < 4; ++h) {
                    float pr[8];
#pragma unroll
                    for (int i = 0; i < 4; ++i) {
                        const f32x4 h2 = obuf[pp][4 * h + i][l];
                        float p0 = 0.f, p1 = 0.f;
#pragma unroll
                        for (int j = 0; j < 4; ++j) {
                            p0 = fmaf(wo0[j], h2[j], p0);
                            p1 = fmaf(wo1[j], h2[j], p1);
                        }
                        p0 += __shfl_xor(p0, 16); p0 += __shfl_xor(p0, 32);
                        p1 += __shfl_xor(p1, 16); p1 += __shfl_xor(p1, 32);
                        pr[2 * i] = p0 + bo0; pr[2 * i + 1] = p1 + bo1;
                    }
                    if (g == 0) {
                        float* op = out + (size_t)b * (TT * 2) + (t0 + 4 * h) * 2;
                        *(float4*)(op)     = make_float4(pr[0], pr[1], pr[2], pr[3]);
                        *(float4*)(op + 4) = make_float4(pr[4], pr[5], pr[6], pr[7]);
                    }
                }
            }
        }
        // LDS-only barrier: drain ds ops, fence compiler, s_barrier.
        // vm loads/stores (x prefetch, out stores) deliberately stay in flight.
        asm volatile("s_waitcnt lgkmcnt(0)\n\ts_barrier" ::: "memory");
    }

    // Final hidden state: layer waves store their own layer.
    if (wid < 3)
        *(f32x4*)(out + (size_t)BB * TT * 2 + ((size_t)wid * BB + b) * 16 + 4 * g) = hC;

#undef GATES
#undef HANDOFF
#undef HB
}

extern "C" void kernel_launch(void* const* d_in, const int* in_sizes, int n_in,
                              void* d_out, int out_size, void* d_ws, size_t ws_size,
                              hipStream_t stream) {
    const float* x     = (const float*)d_in[0];
    const float* h0    = (const float*)d_in[1];
    const float* W_emb = (const float*)d_in[2];
    const float* b_emb = (const float*)d_in[3];
    const float* W_out = (const float*)d_in[4];
    const float* b_out = (const float*)d_in[5];
    const float* Wih0  = (const float*)d_in[6];
    const float* Whh0  = (const float*)d_in[7];
    const float* bih0  = (const float*)d_in[8];
    const float* bhh0  = (const float*)d_in[9];
    const float* Wih1  = (const float*)d_in[10];
    const float* Whh1  = (const float*)d_in[11];
    const float* bih1  = (const float*)d_in[12];
    const float* bhh1  = (const float*)d_in[13];
    const float* Wih2  = (const float*)d_in[14];
    const float* Whh2  = (const float*)d_in[15];
    const float* bih2  = (const float*)d_in[16];
    const float* bhh2  = (const float*)d_in[17];
    float* out = (float*)d_out;

    gru_p16_kernel<<<dim3(BB / 16), dim3(256), 0, stream>>>(
        x, h0, W_emb, b_emb, W_out, b_out,
        Wih0, Whh0, bih0, bhh0,
        Wih1, Whh1, bih1, bhh1,
        Wih2, Whh2, bih2, bhh2,
        out);
}